// Round 9
// baseline (50.128 us; speedup 1.0000x reference)
//
#include <hip/hip_runtime.h>
#include <stdint.h>

// SKA: out[n, g*CW+cw, h, w] = sum_{a,b in 0..2} x[n, g*CW+cw, h+a-1, w+b-1] * w[n, cw, a*3+b, h, w]
// x: (8, 256, 96, 96) f32 ; w: (8, 32, 9, 96, 96) f32 ; out: (8, 256, 96, 96) f32
// Round 8: software-pipelined tiles with COUNTED vmcnt (T3+T4). Block = 1 wave
// walking 8 consecutive 2-row tiles of one (n,cw) column. ALL global reads via
// global_load_lds (x tile 12 ops + w taps 7 ops = 19), so the manual
// s_waitcnt vmcnt(19) is the only sync: tile t+1's stage stays in flight
// across tile t's compute. Never drain to 0 in the loop.

#define N_  8
#define C_  256
#define H_  96
#define W_  96
#define CW_ 32
#define G_  8
#define PL_ (H_ * W_)   // 9216
#define TILES_ 8        // 2-row tiles per block
#define XFL_ 3072       // x buf floats: 4 rows x 8 g x 96
#define WFL_ 1792       // w buf floats: 9 k x 2 r x 96 = 1728, +64 pad

typedef float f32x4 __attribute__((ext_vector_type(4)));

__global__ __launch_bounds__(64) void SKA_kernel(const float* __restrict__ x,
                                                 const float* __restrict__ wgt,
                                                 float* __restrict__ out) {
    __shared__ float xs[2 * XFL_ + 2 * WFL_];  // [x0][x1][w0][w1] = 38912 B

    const int lane  = threadIdx.x;  // one wave per block
    const int widx  = lane & 31;    // 24 active per half-wave
    const int rowid = lane >> 5;    // 0..1

    // 1536 blocks = 8 XCDs x 192; XCD owns one image n.
    const int b    = blockIdx.x;
    const int lb   = (b & 7) * 192 + (b >> 3);
    const int hcol = lb % 6;          // 16-row column
    const int cw   = (lb / 6) % CW_;
    const int n    = lb / 192;

    const int nc  = (n * C_ + cw) * PL_;
    const int wk0 = (n * CW_ + cw) * 9;

    const int w0a = widx * 4;
    const int w0  = (w0a > W_ - 4) ? (W_ - 4) : w0a;
    const bool active = (widx < 24);

    // per-lane source patterns: x chunks (3 x 256 floats over [g:8][96])
    int xgoff[3], xcol[3];
#pragma unroll
    for (int cc = 0; cc < 3; ++cc) {
        const int wo = cc * 256 + lane * 4;
        xgoff[cc] = (wo / 96) * (CW_ * PL_);
        xcol[cc]  = wo % 96;
    }
    // w chunks (7 x 256 floats over [k:9][r:2][96] = 1728; tail lanes clamped into pad)
    int wkoff[7], wroff[7], wcol[7];
#pragma unroll
    for (int cc = 0; cc < 7; ++cc) {
        int e = cc * 256 + lane * 4;
        if (e > 1724) e = 1724;
        wkoff[cc] = e / 192;
        wroff[cc] = (e % 192) / 96;
        wcol[cc]  = e % 96;
    }

    auto stage = [&](int buf, int t) {
        const int h0t = hcol * 16 + 2 * t;
        const uint32_t xb = (uint32_t)(buf * XFL_);
        // x: rows h0t-1 .. h0t+2 (clamped; OOB rows masked at compute)
#pragma unroll
        for (int r = 0; r < 4; ++r) {
            int row = h0t - 1 + r;
            row = row < 0 ? 0 : (row > H_ - 1 ? H_ - 1 : row);
#pragma unroll
            for (int cc = 0; cc < 3; ++cc) {
                const int off = nc + xgoff[cc] + row * W_ + xcol[cc];
                __builtin_amdgcn_global_load_lds(
                    (const __attribute__((address_space(1))) void*)(uintptr_t)(x + off),
                    (__attribute__((address_space(3))) void*)(uintptr_t)
                        (uint32_t)(uintptr_t)&xs[xb + (r * 3 + cc) * 256],
                    16, 0, 0);
            }
        }
        // w: 9 k-planes x 2 rows
        const uint32_t wb2 = (uint32_t)(2 * XFL_ + buf * WFL_);
#pragma unroll
        for (int cc = 0; cc < 7; ++cc) {
            const int off = ((wk0 + wkoff[cc]) * H_ + h0t + wroff[cc]) * W_ + wcol[cc];
            __builtin_amdgcn_global_load_lds(
                (const __attribute__((address_space(1))) void*)(uintptr_t)(wgt + off),
                (__attribute__((address_space(3))) void*)(uintptr_t)
                    (uint32_t)(uintptr_t)&xs[wb2 + cc * 256],
                16, 0, 0);
        }
    };

    stage(0, 0);  // prologue

#pragma unroll 1
    for (int t = 0; t < TILES_; ++t) {
        const int cur = t & 1;
        if (t + 1 < TILES_) stage(cur ^ 1, t + 1);
        __builtin_amdgcn_sched_barrier(0);
        if (t + 1 < TILES_) {
            asm volatile("s_waitcnt vmcnt(19)" ::: "memory");  // tile t landed; t+1 in flight
        } else {
            asm volatile("s_waitcnt vmcnt(8)" ::: "memory");   // only prev stores newer
        }
        __builtin_amdgcn_sched_barrier(0);

        const int h   = hcol * 16 + 2 * t + rowid;
        const float* xbuf = &xs[cur * XFL_];
        const float* wbuf = &xs[2 * XFL_ + cur * WFL_];

        f32x4 wv[9];
#pragma unroll
        for (int k = 0; k < 9; ++k)
            wv[k] = *reinterpret_cast<const f32x4*>(&wbuf[k * 192 + rowid * 96 + w0]);

        f32x4 acc[G_];
#pragma unroll
        for (int g = 0; g < G_; ++g) acc[g] = (f32x4)(0.f);

#pragma unroll
        for (int a = 0; a < 3; ++a) {
            const int hh = h + a - 1;
            if (hh < 0 || hh >= H_) continue;  // zero-pad rows
            const f32x4 wa = wv[a * 3 + 0];
            const f32x4 wm = wv[a * 3 + 1];
            const f32x4 wc = wv[a * 3 + 2];
#pragma unroll
            for (int g = 0; g < G_; ++g) {
                const f32x4 xm = *reinterpret_cast<const f32x4*>(
                    &xbuf[(rowid + a) * (G_ * W_) + g * W_ + w0]);
                float xl = __shfl(xm.w, lane - 1);
                float xr = __shfl(xm.x, lane + 1);
                xl = (widx == 0) ? 0.f : xl;   // x[-1] pad
                xr = (widx == 23) ? 0.f : xr;  // x[96] pad
                acc[g].x = fmaf(xl,   wa.x, acc[g].x);
                acc[g].x = fmaf(xm.x, wm.x, acc[g].x);
                acc[g].x = fmaf(xm.y, wc.x, acc[g].x);
                acc[g].y = fmaf(xm.x, wa.y, acc[g].y);
                acc[g].y = fmaf(xm.y, wm.y, acc[g].y);
                acc[g].y = fmaf(xm.z, wc.y, acc[g].y);
                acc[g].z = fmaf(xm.y, wa.z, acc[g].z);
                acc[g].z = fmaf(xm.z, wm.z, acc[g].z);
                acc[g].z = fmaf(xm.w, wc.z, acc[g].z);
                acc[g].w = fmaf(xm.z, wa.w, acc[g].w);
                acc[g].w = fmaf(xm.w, wm.w, acc[g].w);
                acc[g].w = fmaf(xr,   wc.w, acc[g].w);
            }
        }

        if (active) {
            float* ob = out + nc + h * W_ + w0a;
#pragma unroll
            for (int g = 0; g < G_; ++g)
                __builtin_nontemporal_store(acc[g],
                    reinterpret_cast<f32x4*>(ob + g * (CW_ * PL_)));
        }
    }
}

extern "C" void kernel_launch(void* const* d_in, const int* in_sizes, int n_in,
                              void* d_out, int out_size, void* d_ws, size_t ws_size,
                              hipStream_t stream) {
    const float* x   = (const float*)d_in[0];
    const float* wgt = (const float*)d_in[1];
    float* out = (float*)d_out;

    constexpr int grid = N_ * CW_ * 6;  // 1536 blocks x 64 threads, 8 tiles each
    SKA_kernel<<<grid, 64, 0, stream>>>(x, wgt, out);
}

// Round 11
// 44.062 us; speedup vs baseline: 1.1377x; 1.1377x over previous
//
#include <hip/hip_runtime.h>
#include <stdint.h>

// SKA: out[n, g*CW+cw, h, w] = sum_{a,b in 0..2} x[n, g*CW+cw, h+a-1, w+b-1] * w[n, cw, a*3+b, h, w]
// x: (8, 256, 96, 96) f32 ; w: (8, 32, 9, 96, 96) f32 ; out: (8, 256, 96, 96) f32
// Round 10: Round-9 design (one latency window per wave via order-pinned
// volatile-asm loads) with the swizzle bug fixed: n = t1/32 (was t1/384,
// which mapped every block to image 0 and left images 1..7 zero).

#define N_  8
#define C_  256
#define H_  96
#define W_  96
#define CW_ 32
#define G_  8
#define PL_ (H_ * W_)  // 9216

typedef float f32x4 __attribute__((ext_vector_type(4)));

// order-pinned 16B global load (compiler cannot sink/reorder volatile asm)
#define GLD(dst, addr) \
    asm volatile("global_load_dwordx4 %0, %1, off" : "=v"(dst) : "v"(addr))

__global__ __launch_bounds__(256) void SKA_kernel(const float* __restrict__ x,
                                                  const float* __restrict__ wgt,
                                                  float* __restrict__ out) {
    const int tid   = threadIdx.x;
    const int widx  = tid & 31;   // 0..31, 24 active (w0 = 4*widx < 96)
    const int rowid = tid >> 5;   // 0..7
    const int lane  = tid & 63;

    // XCD-bijective swizzle: 3072 blocks = 8 XCDs x 384; each XCD owns one image n.
    const int b  = blockIdx.x;
    const int lb = (b & 7) * 384 + (b >> 3);
    const int ht = lb % 12;
    const int t1 = lb / 12;       // 0..255
    const int cw = t1 % CW_;
    const int n  = t1 / CW_;      // 0..7  (R9 bug: was t1/384 == 0 always)
    const int h  = ht * 8 + rowid;
    const int w0 = widx * 4;

    if (widx >= 24) return;

    // ---- 9 per-pixel kernel taps (compiler-scheduled; reused across 8 groups) ----
    const float* wb = wgt + (size_t)(((n * CW_ + cw) * 9) * H_ + h) * W_ + w0;
    f32x4 wv[9];
#pragma unroll
    for (int k = 0; k < 9; ++k)
        wv[k] = *reinterpret_cast<const f32x4*>(wb + k * PL_);

    // ---- 24 order-pinned x loads: ALL in flight before one waitcnt ----
    const float* xb = x + (size_t)((n * C_ + cw) * PL_) + w0;
    const int r0 = (h - 1 < 0) ? 0 : h - 1;        // clamped; OOB rows masked at compute
    const int r2 = (h + 1 >= H_) ? H_ - 1 : h + 1;
    const int rows[3] = {r0, h, r2};

    f32x4 xm[3][G_];
#pragma unroll
    for (int a = 0; a < 3; ++a) {
#pragma unroll
        for (int g = 0; g < G_; ++g) {
            GLD(xm[a][g], xb + (size_t)(g * CW_) * PL_ + rows[a] * W_);
        }
    }

    // single drain of the pinned loads; fence consumer hoisting (rule #18)
    asm volatile("s_waitcnt vmcnt(0)" ::: "memory");
    __builtin_amdgcn_sched_barrier(0);

    // ---- compute (R4/R5-validated shfl-halo FMA chain) ----
    f32x4 acc[G_];
#pragma unroll
    for (int g = 0; g < G_; ++g) acc[g] = (f32x4)(0.f);

#pragma unroll
    for (int a = 0; a < 3; ++a) {
        const int hh = h + a - 1;
        if (hh < 0 || hh >= H_) continue;  // zero-pad rows
        const f32x4 wa = wv[a * 3 + 0];
        const f32x4 wm = wv[a * 3 + 1];
        const f32x4 wc = wv[a * 3 + 2];
#pragma unroll
        for (int g = 0; g < G_; ++g) {
            const f32x4 xv = xm[a][g];
            float xl = __shfl(xv.w, lane - 1);
            float xr = __shfl(xv.x, lane + 1);
            xl = (widx == 0) ? 0.f : xl;   // x[-1] pad
            xr = (widx == 23) ? 0.f : xr;  // x[96] pad
            acc[g].x = fmaf(xl,   wa.x, acc[g].x);
            acc[g].x = fmaf(xv.x, wm.x, acc[g].x);
            acc[g].x = fmaf(xv.y, wc.x, acc[g].x);
            acc[g].y = fmaf(xv.x, wa.y, acc[g].y);
            acc[g].y = fmaf(xv.y, wm.y, acc[g].y);
            acc[g].y = fmaf(xv.z, wc.y, acc[g].y);
            acc[g].z = fmaf(xv.y, wa.z, acc[g].z);
            acc[g].z = fmaf(xv.z, wm.z, acc[g].z);
            acc[g].z = fmaf(xv.w, wc.z, acc[g].z);
            acc[g].w = fmaf(xv.z, wa.w, acc[g].w);
            acc[g].w = fmaf(xv.w, wm.w, acc[g].w);
            acc[g].w = fmaf(xr,   wc.w, acc[g].w);
        }
    }

    float* ob = out + (size_t)((n * C_ + cw) * PL_) + h * W_ + w0;
#pragma unroll
    for (int g = 0; g < G_; ++g) {
        __builtin_nontemporal_store(
            acc[g], reinterpret_cast<f32x4*>(ob + (size_t)(g * CW_) * PL_));
    }
}

extern "C" void kernel_launch(void* const* d_in, const int* in_sizes, int n_in,
                              void* d_out, int out_size, void* d_ws, size_t ws_size,
                              hipStream_t stream) {
    const float* x   = (const float*)d_in[0];
    const float* wgt = (const float*)d_in[1];
    float* out = (float*)d_out;

    constexpr int grid = N_ * CW_ * (H_ / 8);  // 3072 blocks x 256 threads
    SKA_kernel<<<grid, 256, 0, stream>>>(x, wgt, out);
}

// Round 12
// 41.488 us; speedup vs baseline: 1.2083x; 1.0620x over previous
//
#include <hip/hip_runtime.h>
#include <stdint.h>

// SKA: out[n, g*CW+cw, h, w] = sum_{a,b in 0..2} x[n, g*CW+cw, h+a-1, w+b-1] * w[n, cw, a*3+b, h, w]
// x: (8, 256, 96, 96) f32 ; w: (8, 32, 9, 96, 96) f32 ; out: (8, 256, 96, 96) f32
// Round 11: DRAM-locality tuning of the R10 structure. Evidence R4/R7/R10 all
// land ~43-44us with totally different MLP => per-CU request cap x latency is
// the limiter; only locality can cut latency. Changes: (1) x loads issued
// g-outer/a-inner so each group's 3 window rows form a ~1.2KB contiguous
// cluster (row-buffer hits), (2) plain stores (L2-absorbed) instead of NT,
// (3) keep XCD swizzle + order-pinned asm loads.

#define N_  8
#define C_  256
#define H_  96
#define W_  96
#define CW_ 32
#define G_  8
#define PL_ (H_ * W_)  // 9216

typedef float f32x4 __attribute__((ext_vector_type(4)));

// order-pinned 16B global load (compiler cannot sink/reorder volatile asm)
#define GLD(dst, addr) \
    asm volatile("global_load_dwordx4 %0, %1, off" : "=v"(dst) : "v"(addr))

__global__ __launch_bounds__(256) void SKA_kernel(const float* __restrict__ x,
                                                  const float* __restrict__ wgt,
                                                  float* __restrict__ out) {
    const int tid   = threadIdx.x;
    const int widx  = tid & 31;   // 0..31, 24 active (w0 = 4*widx < 96)
    const int rowid = tid >> 5;   // 0..7
    const int lane  = tid & 63;

    // XCD-bijective swizzle: 3072 blocks = 8 XCDs x 384; each XCD owns one image n.
    const int b  = blockIdx.x;
    const int lb = (b & 7) * 384 + (b >> 3);
    const int ht = lb % 12;
    const int t1 = lb / 12;       // 0..255
    const int cw = t1 % CW_;
    const int n  = t1 / CW_;      // 0..7
    const int h  = ht * 8 + rowid;
    const int w0 = widx * 4;

    if (widx >= 24) return;

    // ---- 9 per-pixel kernel taps (issued first, oldest in VMEM queue) ----
    const float* wb = wgt + (size_t)(((n * CW_ + cw) * 9) * H_ + h) * W_ + w0;
    f32x4 wv[9];
#pragma unroll
    for (int k = 0; k < 9; ++k)
        wv[k] = *reinterpret_cast<const f32x4*>(wb + k * PL_);
    __builtin_amdgcn_sched_barrier(0);  // pin wv issue before the x batch

    // ---- 24 order-pinned x loads, g-outer / a-inner: per-group the 3 window
    // rows are 384B apart -> ~1.2KB contiguous DRAM cluster per group ----
    const float* xb = x + (size_t)((n * C_ + cw) * PL_) + w0;
    const int r0 = (h - 1 < 0) ? 0 : h - 1;        // clamped; OOB rows masked at compute
    const int r2 = (h + 1 >= H_) ? H_ - 1 : h + 1;
    const int rows[3] = {r0, h, r2};

    f32x4 xm[3][G_];
#pragma unroll
    for (int g = 0; g < G_; ++g) {
        const float* xg = xb + (size_t)(g * CW_) * PL_;
#pragma unroll
        for (int a = 0; a < 3; ++a) {
            GLD(xm[a][g], xg + rows[a] * W_);
        }
    }

    // single drain of the pinned loads; fence consumer hoisting (rule #18)
    asm volatile("s_waitcnt vmcnt(0)" ::: "memory");
    __builtin_amdgcn_sched_barrier(0);

    // ---- compute (R4/R5-validated shfl-halo FMA chain) ----
    f32x4 acc[G_];
#pragma unroll
    for (int g = 0; g < G_; ++g) acc[g] = (f32x4)(0.f);

#pragma unroll
    for (int a = 0; a < 3; ++a) {
        const int hh = h + a - 1;
        if (hh < 0 || hh >= H_) continue;  // zero-pad rows
        const f32x4 wa = wv[a * 3 + 0];
        const f32x4 wm = wv[a * 3 + 1];
        const f32x4 wc = wv[a * 3 + 2];
#pragma unroll
        for (int g = 0; g < G_; ++g) {
            const f32x4 xv = xm[a][g];
            float xl = __shfl(xv.w, lane - 1);
            float xr = __shfl(xv.x, lane + 1);
            xl = (widx == 0) ? 0.f : xl;   // x[-1] pad
            xr = (widx == 23) ? 0.f : xr;  // x[96] pad
            acc[g].x = fmaf(xl,   wa.x, acc[g].x);
            acc[g].x = fmaf(xv.x, wm.x, acc[g].x);
            acc[g].x = fmaf(xv.y, wc.x, acc[g].x);
            acc[g].y = fmaf(xv.x, wa.y, acc[g].y);
            acc[g].y = fmaf(xv.y, wm.y, acc[g].y);
            acc[g].y = fmaf(xv.z, wc.y, acc[g].y);
            acc[g].z = fmaf(xv.y, wa.z, acc[g].z);
            acc[g].z = fmaf(xv.z, wm.z, acc[g].z);
            acc[g].z = fmaf(xv.w, wc.z, acc[g].z);
            acc[g].w = fmaf(xv.z, wa.w, acc[g].w);
            acc[g].w = fmaf(xv.w, wm.w, acc[g].w);
            acc[g].w = fmaf(xr,   wc.w, acc[g].w);
        }
    }

    // plain stores: let L2 absorb and drain lazily (NT pushed scattered writes
    // into the latency path)
    float* ob = out + (size_t)((n * C_ + cw) * PL_) + h * W_ + w0;
#pragma unroll
    for (int g = 0; g < G_; ++g) {
        *reinterpret_cast<f32x4*>(ob + (size_t)(g * CW_) * PL_) = acc[g];
    }
}

extern "C" void kernel_launch(void* const* d_in, const int* in_sizes, int n_in,
                              void* d_out, int out_size, void* d_ws, size_t ws_size,
                              hipStream_t stream) {
    const float* x   = (const float*)d_in[0];
    const float* wgt = (const float*)d_in[1];
    float* out = (float*)d_out;

    constexpr int grid = N_ * CW_ * (H_ / 8);  // 3072 blocks x 256 threads
    SKA_kernel<<<grid, 256, 0, stream>>>(x, wgt, out);
}